// Round 4
// baseline (358.180 us; speedup 1.0000x reference)
//
#include <hip/hip_runtime.h>

// Problem constants (from reference)
#define NC 32768
#define ND 1024
#define NQ 256    // float4 chunks per row (ND/4)
#define NB 16384
#define KEEP 0.95f
#define OMK  0.05f   // 1 - keep
#define KCAP 16      // per-class sample-list cap; P(Poisson(0.5) >= 17) ~ 1e-19
#define JPAD 2       // unconditionally-gathered entries per row (weight-0 padded)
#define RPB  4       // rows per block in loss kernel

typedef float fx4 __attribute__((ext_vector_type(4)));  // native vector: nontemporal-load-able

// Kernel 1: count occurrences per class, scatter sample indices into
// per-class lists (order arbitrary; the index itself encodes batch order).
__global__ void count_scatter_kernel(const int* __restrict__ the_class,
                                     int* __restrict__ counts,
                                     int* __restrict__ idx_list) {
    int i = blockIdx.x * blockDim.x + threadIdx.x;
    if (i < NB) {
        int c = the_class[i];
        int pos = atomicAdd(&counts[c], 1);
        if (pos < KCAP) idx_list[c * KCAP + pos] = i;
    }
}

// Kernel 2: per-class EMA metadata. One thread per class.
// decays[c] = keep^cnt; elist[c][j] = {sample_idx, (1-keep)*keep^{#later occ}}
// Entries j >= cnt are PADDED with {0, 0.0f} so the loss kernel can gather
// the first JPAD entries unconditionally (weight 0 -> no contribution;
// logits row 0 stays L2-resident).
__global__ void wprep_kernel(const int* __restrict__ counts,
                             const int* __restrict__ idx_list,
                             float* __restrict__ decays,
                             int2* __restrict__ elist) {
    int c = blockIdx.x * blockDim.x + threadIdx.x;
    int cnt = counts[c];
    float base = KEEP, r = 1.0f;
    for (int e = cnt; e > 0; e >>= 1) { if (e & 1) r *= base; base *= base; }
    decays[c] = r;
    int m = cnt < KCAP ? cnt : KCAP;
    int idx[KCAP];
    for (int j = 0; j < m; ++j) idx[j] = idx_list[c * KCAP + j];
    for (int j = 0; j < KCAP; ++j) {
        int2 e;
        if (j < m) {
            int later = 0;
            for (int l = 0; l < m; ++l) later += (idx[l] > idx[j]);
            float w = OMK;
            for (int k = 0; k < later; ++k) w *= KEEP;
            e.x = idx[j]; e.y = __float_as_int(w);
        } else {
            e.x = 0; e.y = __float_as_int(0.0f);
        }
        elist[c * KCAP + j] = e;
    }
}

// Kernel 3: fused EMA + L1 loss. Block = 256 threads handles RPB=4 rows;
// thread q owns float4 column q. ALL 16 wave-loads (4 s + 4 t + 8 padded
// gathers) are independent and issued before any consumer -> 16 KB/wave
// in flight. Rare rows with cnt > JPAD take a runtime tail loop.
__global__ __launch_bounds__(256) void loss_kernel(
    const float* __restrict__ s_logits,
    const float* __restrict__ t_logits,
    const float* __restrict__ logits,
    const int*   __restrict__ counts,
    const float* __restrict__ decays,
    const int2*  __restrict__ elist,
    float* __restrict__ out) {

    const int q  = threadIdx.x;        // float4 column 0..255
    const int c0 = blockIdx.x * RPB;

    const fx4* s4 = (const fx4*)s_logits;
    const fx4* t4 = (const fx4*)t_logits;
    const fx4* l4 = (const fx4*)logits;

    // Per-row metadata (wave-uniform -> scalar loads)
    float dec[RPB]; int m[RPB]; int2 ge[RPB][JPAD];
    #pragma unroll
    for (int r = 0; r < RPB; ++r) {
        dec[r] = decays[c0 + r];
        int cnt = counts[c0 + r];
        m[r] = cnt < KCAP ? cnt : KCAP;
        #pragma unroll
        for (int j = 0; j < JPAD; ++j) ge[r][j] = elist[(c0 + r) * KCAP + j];
    }

    // Issue all independent loads up front.
    fx4 sv[RPB], tv[RPB], gv[RPB][JPAD];
    #pragma unroll
    for (int r = 0; r < RPB; ++r)
        sv[r] = __builtin_nontemporal_load(&s4[(size_t)(c0 + r) * NQ + q]);
    #pragma unroll
    for (int r = 0; r < RPB; ++r)
        tv[r] = __builtin_nontemporal_load(&t4[(size_t)(c0 + r) * NQ + q]);
    #pragma unroll
    for (int r = 0; r < RPB; ++r) {
        #pragma unroll
        for (int j = 0; j < JPAD; ++j)
            gv[r][j] = l4[(size_t)ge[r][j].x * NQ + q];
    }

    float lsum = 0.0f;
    #pragma unroll
    for (int r = 0; r < RPB; ++r) {
        fx4 acc = sv[r] * dec[r];
        #pragma unroll
        for (int j = 0; j < JPAD; ++j) {
            const float w = __int_as_float(ge[r][j].y);   // 0 for padded entries
            acc.x = fmaf(w, gv[r][j].x, acc.x);
            acc.y = fmaf(w, gv[r][j].y, acc.y);
            acc.z = fmaf(w, gv[r][j].z, acc.z);
            acc.w = fmaf(w, gv[r][j].w, acc.w);
        }
        // Rare tail: classes with more than JPAD samples (~1.4%)
        if (m[r] > JPAD) {
            for (int j = JPAD; j < m[r]; ++j) {
                int2 e = elist[(c0 + r) * KCAP + j];
                const float w = __int_as_float(e.y);
                fx4 lv = l4[(size_t)e.x * NQ + q];
                acc.x = fmaf(w, lv.x, acc.x);
                acc.y = fmaf(w, lv.y, acc.y);
                acc.z = fmaf(w, lv.z, acc.z);
                acc.w = fmaf(w, lv.w, acc.w);
            }
        }
        lsum += fabsf(acc.x - tv[r].x) + fabsf(acc.y - tv[r].y) +
                fabsf(acc.z - tv[r].z) + fabsf(acc.w - tv[r].w);
    }

    // Wave reduction (64 lanes) then cross-wave via LDS.
    #pragma unroll
    for (int off = 32; off > 0; off >>= 1) lsum += __shfl_down(lsum, off);
    __shared__ float wsum[4];
    const int wave = threadIdx.x >> 6, lane = threadIdx.x & 63;
    if (lane == 0) wsum[wave] = lsum;
    __syncthreads();
    if (threadIdx.x == 0) {
        float total = (wsum[0] + wsum[1] + wsum[2] + wsum[3]) * (1.0f / NC);
        atomicAdd(out, total);
    }
}

extern "C" void kernel_launch(void* const* d_in, const int* in_sizes, int n_in,
                              void* d_out, int out_size, void* d_ws, size_t ws_size,
                              hipStream_t stream) {
    const float* s_logits  = (const float*)d_in[0];
    const float* t_logits  = (const float*)d_in[1];
    const float* logits    = (const float*)d_in[2];
    const int*   the_class = (const int*)d_in[3];
    float* out = (float*)d_out;

    int*   counts   = (int*)d_ws;                      // NC ints   (128 KB)
    int*   idx_list = counts + NC;                     // NC*KCAP   (2 MB)
    float* decays   = (float*)(idx_list + NC * KCAP);  // NC floats (128 KB)
    int2*  elist    = (int2*)(decays + NC);            // NC*KCAP int2 (4 MB)

    (void)hipMemsetAsync(counts, 0, NC * sizeof(int), stream);
    (void)hipMemsetAsync(d_out, 0, sizeof(float), stream);

    count_scatter_kernel<<<NB / 256, 256, 0, stream>>>(the_class, counts, idx_list);
    wprep_kernel<<<NC / 256, 256, 0, stream>>>(counts, idx_list, decays, elist);
    loss_kernel<<<NC / RPB, 256, 0, stream>>>(s_logits, t_logits, logits,
                                              counts, decays, elist, out);
}